// Round 1
// baseline (967.888 us; speedup 1.0000x reference)
//
#include <hip/hip_runtime.h>

// ---- problem constants (pinned by reference) ----
#define NN    20000      // nodes
#define NE    5000       // hyperedges
#define NNZ_  200000     // incidences
#define DD    6          // sheaf dim d (heads)
#define HH    9          // MLP hidden
#define DHID  54         // DD*HH
#define FIN   256        // input features
#define ODIM  4968       // output features
#define NCAP  64         // node bucket capacity (mean deg 10)
#define ECAP  128        // edge bucket capacity (mean deg 40)

// ---------------------------------------------------------------------------
// proj: row i of `in` (FIN floats) @ lin_w (FIN x 54) + lin_b -> proj row (54)
// also emits per-d mean (9 floats). One 64-thread block per row.
// ---------------------------------------------------------------------------
__global__ __launch_bounds__(64) void proj_kernel(
    const float* __restrict__ in, const float* __restrict__ w,
    const float* __restrict__ b, float* __restrict__ proj_out,
    float* __restrict__ mean_out)
{
    const int i = blockIdx.x;
    const int t = threadIdx.x;
    __shared__ float xrow[FIN];
    __shared__ float prow[DHID];

    // 256 floats = 64 lanes x float4, coalesced
    ((float4*)xrow)[t] = ((const float4*)(in + (size_t)i * FIN))[t];
    __syncthreads();

    if (t < DHID) {
        float acc = b[t];
        #pragma unroll 4
        for (int k = 0; k < FIN; ++k)
            acc += xrow[k] * w[k * DHID + t];
        prow[t] = acc;
        if (proj_out) proj_out[(size_t)i * DHID + t] = acc;
    }
    __syncthreads();
    if (t < HH) {
        float s = 0.f;
        #pragma unroll
        for (int r = 0; r < DD; ++r) s += prow[r * HH + t];
        mean_out[(size_t)i * HH + t] = s * (1.0f / DD);
    }
}

// ---------------------------------------------------------------------------
// Build incidence buckets + degree counts (once per launch; indices static).
// ---------------------------------------------------------------------------
__global__ void fill_kernel(const int* __restrict__ node_idx,
                            const int* __restrict__ edge_idx,
                            int* __restrict__ ncnt, int* __restrict__ ecnt,
                            int* __restrict__ nbuck, int* __restrict__ ebuck)
{
    int nz = blockIdx.x * blockDim.x + threadIdx.x;
    if (nz >= NNZ_) return;
    int n = node_idx[nz], e = edge_idx[nz];
    int p = atomicAdd(&ncnt[n], 1);
    if (p < NCAP) nbuck[n * NCAP + p] = nz;
    int q = atomicAdd(&ecnt[e], 1);
    if (q < ECAP) ebuck[e * ECAP + q] = nz;
}

__global__ void inv_kernel(const int* __restrict__ ncnt, const int* __restrict__ ecnt,
                           float* __restrict__ ninv, float* __restrict__ einv)
{
    int i = blockIdx.x * blockDim.x + threadIdx.x;
    if (i < NN) {
        int c = ncnt[i];
        ninv[i] = (c > 0) ? 1.0f / (float)c : 0.0f;
    }
    int j = i - NN;
    if (j >= 0 && j < NE) {
        int c = ecnt[j];
        einv[j] = (c > 0) ? 1.0f / (float)c : 0.0f;
    }
}

// ---------------------------------------------------------------------------
// Sheaf: per incidence, LN(concat(xm[n], em[e])) @ sheaf_w + b, sigmoid -> alpha[6]
// ---------------------------------------------------------------------------
__global__ void sheaf_kernel(const int* __restrict__ node_idx,
                             const int* __restrict__ edge_idx,
                             const float* __restrict__ xm, const float* __restrict__ em,
                             const float* __restrict__ g, const float* __restrict__ b,
                             const float* __restrict__ w, const float* __restrict__ bb,
                             float* __restrict__ alpha)
{
    int nz = blockIdx.x * blockDim.x + threadIdx.x;
    if (nz >= NNZ_) return;
    float p[18];
    const float* xr = xm + (size_t)node_idx[nz] * HH;
    const float* er = em + (size_t)edge_idx[nz] * HH;
    #pragma unroll
    for (int h = 0; h < HH; ++h) { p[h] = xr[h]; p[HH + h] = er[h]; }

    float mean = 0.f;
    #pragma unroll
    for (int k = 0; k < 18; ++k) mean += p[k];
    mean *= (1.0f / 18.0f);
    float var = 0.f;
    #pragma unroll
    for (int k = 0; k < 18; ++k) { float d = p[k] - mean; var += d * d; }
    var *= (1.0f / 18.0f);
    float rin = rsqrtf(var + 1e-5f);
    #pragma unroll
    for (int k = 0; k < 18; ++k) p[k] = (p[k] - mean) * rin * g[k] + b[k];

    #pragma unroll
    for (int c = 0; c < DD; ++c) {
        float z = bb[c];
        #pragma unroll
        for (int k = 0; k < 18; ++k) z += p[k] * w[k * DD + c];
        alpha[(size_t)nz * DD + c] = 1.0f / (1.0f + expf(-z));
    }
}

// ---------------------------------------------------------------------------
// conv lin: h0 = LN(x) @ W + cb, one thread per expanded row (N*d rows of 9)
// ---------------------------------------------------------------------------
__global__ void conv_lin_kernel(const float* __restrict__ xin,
                                const float* __restrict__ g, const float* __restrict__ b,
                                const float* __restrict__ W, const float* __restrict__ cb,
                                float* __restrict__ h0)
{
    int row = blockIdx.x * blockDim.x + threadIdx.x;
    if (row >= NN * DD) return;
    const float* xr = xin + (size_t)row * HH;
    float v[HH];
    float mean = 0.f;
    #pragma unroll
    for (int k = 0; k < HH; ++k) { v[k] = xr[k]; mean += v[k]; }
    mean *= (1.0f / HH);
    float var = 0.f;
    #pragma unroll
    for (int k = 0; k < HH; ++k) { float d = v[k] - mean; var += d * d; }
    var *= (1.0f / HH);
    float rin = rsqrtf(var + 1e-5f);
    float ln[HH];
    #pragma unroll
    for (int k = 0; k < HH; ++k) ln[k] = (v[k] - mean) * rin * g[k] + b[k];
    #pragma unroll
    for (int j = 0; j < HH; ++j) {
        float s = cb[j];
        #pragma unroll
        for (int k = 0; k < HH; ++k) s += ln[k] * W[k * HH + j];
        h0[(size_t)row * HH + j] = s;
    }
}

// ---------------------------------------------------------------------------
// node -> edge aggregation: m[e*6+rd][h] = einv[e] * sum alpha * h0[n*6+rd][h]
// one thread per (edge-row, h): 30000*9 threads, gather over bucket.
// ---------------------------------------------------------------------------
__global__ void edge_agg_kernel(const int* __restrict__ ecnt, const int* __restrict__ ebuck,
                                const int* __restrict__ node_idx,
                                const float* __restrict__ alpha,
                                const float* __restrict__ h0,
                                const float* __restrict__ einv,
                                float* __restrict__ m)
{
    int t = blockIdx.x * blockDim.x + threadIdx.x;
    if (t >= NE * DD * HH) return;
    int h = t % HH;
    int er = t / HH;          // e*6+rd
    int e = er / DD;
    int rd = er - e * DD;
    int cnt = ecnt[e];
    if (cnt > ECAP) cnt = ECAP;
    const int* bl = ebuck + (size_t)e * ECAP;
    float s = 0.f;
    for (int j = 0; j < cnt; ++j) {
        int nz = bl[j];
        float a = alpha[(size_t)nz * DD + rd];
        int n = node_idx[nz];
        s += a * h0[((size_t)n * DD + rd) * HH + h];
    }
    m[(size_t)t] = s * einv[e];
}

// ---------------------------------------------------------------------------
// edge -> node aggregation fused with residual+bias+activation:
// xout = act( ninv[n] * sum alpha*m[col] + h0 + conv_bias )
// ---------------------------------------------------------------------------
__global__ void node_agg_kernel(const int* __restrict__ ncnt, const int* __restrict__ nbuck,
                                const int* __restrict__ edge_idx,
                                const float* __restrict__ alpha,
                                const float* __restrict__ m,
                                const float* __restrict__ ninv,
                                const float* __restrict__ h0,
                                const float* __restrict__ cbias,
                                float* __restrict__ xout, int do_elu)
{
    int t = blockIdx.x * blockDim.x + threadIdx.x;
    if (t >= NN * DD * HH) return;
    int h = t % HH;
    int row = t / HH;         // n*6+rd
    int n = row / DD;
    int rd = row - n * DD;
    int cnt = ncnt[n];
    if (cnt > NCAP) cnt = NCAP;
    const int* bl = nbuck + (size_t)n * NCAP;
    float s = 0.f;
    for (int j = 0; j < cnt; ++j) {
        int nz = bl[j];
        float a = alpha[(size_t)nz * DD + rd];
        int e = edge_idx[nz];
        s += a * m[((size_t)e * DD + rd) * HH + h];
    }
    float v = s * ninv[n] + h0[t] + cbias[h];
    if (do_elu) v = (v > 0.f) ? v : (expf(v) - 1.0f);
    xout[t] = v;
}

// ---------------------------------------------------------------------------
// final GEMM: C[20000,4968] = A[20000,54] @ W[54,4968] + bias
// 128x128 tile per 256-thread block, 8x8 per thread via split 4+4 quads.
// ---------------------------------------------------------------------------
__global__ __launch_bounds__(256) void gemm_lin2(
    const float* __restrict__ A, const float* __restrict__ W,
    const float* __restrict__ bias, float* __restrict__ C)
{
    __shared__ float As[DHID][132];
    __shared__ float Bs[DHID][132];
    const int t = threadIdx.x;
    const int col0 = blockIdx.x * 128;
    const int row0 = blockIdx.y * 128;

    // B tile: 54x128, coalesced
    for (int idx = t; idx < DHID * 128; idx += 256) {
        int k = idx >> 7, c = idx & 127;
        int gc = col0 + c;
        Bs[k][c] = (gc < ODIM) ? W[(size_t)k * ODIM + gc] : 0.f;
    }
    // A tile transposed: contiguous global read (row0*54 + idx)
    for (int idx = t; idx < 128 * DHID; idx += 256) {
        int i = idx / DHID, k = idx - i * DHID;
        int gr = row0 + i;
        As[k][i] = (gr < NN) ? A[(size_t)gr * DHID + k] : 0.f;
    }
    __syncthreads();

    const int cg = t & 15;     // col group 0..15
    const int rg = t >> 4;     // row group 0..15
    float acc[8][8];
    #pragma unroll
    for (int i = 0; i < 8; ++i)
        #pragma unroll
        for (int j = 0; j < 8; ++j) acc[i][j] = 0.f;

    #pragma unroll 2
    for (int k = 0; k < DHID; ++k) {
        float4 a0 = *(const float4*)&As[k][rg * 4];
        float4 a1 = *(const float4*)&As[k][64 + rg * 4];
        float4 b0 = *(const float4*)&Bs[k][cg * 4];
        float4 b1 = *(const float4*)&Bs[k][64 + cg * 4];
        float av[8] = {a0.x, a0.y, a0.z, a0.w, a1.x, a1.y, a1.z, a1.w};
        float bv[8] = {b0.x, b0.y, b0.z, b0.w, b1.x, b1.y, b1.z, b1.w};
        #pragma unroll
        for (int i = 0; i < 8; ++i)
            #pragma unroll
            for (int j = 0; j < 8; ++j)
                acc[i][j] += av[i] * bv[j];
    }

    #pragma unroll
    for (int ih = 0; ih < 2; ++ih)
    #pragma unroll
    for (int ii = 0; ii < 4; ++ii) {
        int gr = row0 + ih * 64 + rg * 4 + ii;
        if (gr >= NN) continue;
        #pragma unroll
        for (int jh = 0; jh < 2; ++jh) {
            int gc = col0 + jh * 64 + cg * 4;
            if (gc >= ODIM) continue;   // ODIM%4==0 -> whole quad in/out
            float4 o;
            o.x = acc[ih * 4 + ii][jh * 4 + 0] + bias[gc + 0];
            o.y = acc[ih * 4 + ii][jh * 4 + 1] + bias[gc + 1];
            o.z = acc[ih * 4 + ii][jh * 4 + 2] + bias[gc + 2];
            o.w = acc[ih * 4 + ii][jh * 4 + 3] + bias[gc + 3];
            *(float4*)&C[(size_t)gr * ODIM + gc] = o;
        }
    }
}

// ---------------------------------------------------------------------------
extern "C" void kernel_launch(void* const* d_in, const int* in_sizes, int n_in,
                              void* d_out, int out_size, void* d_ws, size_t ws_size,
                              hipStream_t stream)
{
    const float* x        = (const float*)d_in[0];
    const float* ha       = (const float*)d_in[1];
    const int*   node_idx = (const int*)d_in[2];
    const int*   edge_idx = (const int*)d_in[3];
    const float* lin_w    = (const float*)d_in[4];
    const float* lin_b    = (const float*)d_in[5];
    const float* sln_g    = (const float*)d_in[6];
    const float* sln_b    = (const float*)d_in[7];
    const float* sheaf_w  = (const float*)d_in[8];
    const float* sheaf_b  = (const float*)d_in[9];
    const float* cln_g    = (const float*)d_in[10];
    const float* cln_b    = (const float*)d_in[11];
    const float* conv_w   = (const float*)d_in[12];
    const float* conv_b   = (const float*)d_in[13];
    const float* conv_bias= (const float*)d_in[14];
    const float* lin2_w   = (const float*)d_in[15];
    const float* lin2_b   = (const float*)d_in[16];
    float* out = (float*)d_out;

    // ---- workspace layout (floats then ints), ~27.7 MB ----
    float* ws = (float*)d_ws;
    float* xp    = ws;                          // NN*54
    float* xb    = xp + (size_t)NN * DHID;      // NN*54
    float* h0    = xb + (size_t)NN * DHID;      // NN*54
    float* xm    = h0 + (size_t)NN * DHID;      // NN*9
    float* em    = xm + (size_t)NN * HH;        // NE*9
    float* alpha = em + (size_t)NE * HH;        // NNZ*6
    float* mbuf  = alpha + (size_t)NNZ_ * DD;   // NE*54
    float* ninv  = mbuf + (size_t)NE * DHID;    // NN
    float* einv  = ninv + NN;                   // NE
    int* ncnt  = (int*)(einv + NE);             // NN
    int* ecnt  = ncnt + NN;                     // NE
    int* nbuck = ecnt + NE;                     // NN*NCAP
    int* ebuck = nbuck + (size_t)NN * NCAP;     // NE*ECAP

    // zero degree counters (ws is poisoned before every call)
    hipMemsetAsync(ncnt, 0, (NN + NE) * sizeof(int), stream);

    // projections + per-d means
    proj_kernel<<<NN, 64, 0, stream>>>(x, lin_w, lin_b, xp, xm);
    proj_kernel<<<NE, 64, 0, stream>>>(ha, lin_w, lin_b, nullptr, em);

    // incidence buckets + degrees
    fill_kernel<<<(NNZ_ + 255) / 256, 256, 0, stream>>>(node_idx, edge_idx,
                                                        ncnt, ecnt, nbuck, ebuck);
    inv_kernel<<<(NN + NE + 255) / 256, 256, 0, stream>>>(ncnt, ecnt, ninv, einv);

    // sheaf attributes (static across layers)
    sheaf_kernel<<<(NNZ_ + 255) / 256, 256, 0, stream>>>(
        node_idx, edge_idx, xm, em, sln_g, sln_b, sheaf_w, sheaf_b, alpha);

    // conv layers
    const float* xin = xp;
    float* xout = xb;
    for (int l = 0; l < 2; ++l) {
        conv_lin_kernel<<<(NN * DD + 255) / 256, 256, 0, stream>>>(
            xin, cln_g + l * HH, cln_b + l * HH, conv_w + l * HH * HH,
            conv_b + l * HH, h0);
        edge_agg_kernel<<<(NE * DD * HH + 255) / 256, 256, 0, stream>>>(
            ecnt, ebuck, node_idx, alpha, h0, einv, mbuf);
        node_agg_kernel<<<(NN * DD * HH + 255) / 256, 256, 0, stream>>>(
            ncnt, nbuck, edge_idx, alpha, mbuf, ninv, h0,
            conv_bias + l * HH, xout, (l == 0) ? 1 : 0);
        const float* tmp = xin; xin = xout; xout = (float*)tmp;
    }

    // final GEMM: xin is the layer-2 output, (NN, 54) contiguous
    dim3 grid((ODIM + 127) / 128, (NN + 127) / 128);
    gemm_lin2<<<grid, 256, 0, stream>>>(xin, lin2_w, lin2_b, out);
}